// Round 3
// baseline (1279.514 us; speedup 1.0000x reference)
//
#include <hip/hip_runtime.h>
#include <hip/hip_bf16.h>
#include <math.h>

// Problem constants (B=4, T=1024, H=1024, V=32000)
constexpr int kH   = 1024;    // also row stride in fp8 BYTES
constexpr int kV   = 32000;
constexpr int kTok = 4096;    // B*T
constexpr int BM   = 128;
constexpr int BN   = 128;
constexpr int BKB  = 128;     // K-step in fp8 bytes
constexpr int NVT  = kV / BN;    // 250
constexpr int NMT  = kTok / BM;  // 32

typedef int   v8i  __attribute__((ext_vector_type(8)));
typedef float f32x4 __attribute__((ext_vector_type(4)));

typedef __attribute__((address_space(1))) const void gvoid_t;
typedef __attribute__((address_space(3))) void lvoid_t;

// fp32 -> fp8 e4m3 (OCP, HW cvt) with XOR-swizzled 16B blocks: within each
// 128-byte K-chunk, logical 16B block c of row r lands at block c ^ (r & 7).
// GEMM staging stays linear; fragment ds_read_b128 spreads over 8 bank groups.
// One dispatch converts all four arrays: block ranges [0,1024) x, [1024,9024) w,
// [9024,10048) rx, [10048,18048) rw.
__global__ __launch_bounds__(256) void convert_kernel(
    const float* __restrict__ x,  char* __restrict__ xd,
    const float* __restrict__ w,  char* __restrict__ wd,
    const float* __restrict__ rx, char* __restrict__ rxd,
    const float* __restrict__ rw, char* __restrict__ rwd)
{
  int bid = blockIdx.x;
  const float* src;
  char* dst;
  if (bid < 1024)       { src = x;  dst = xd; }
  else if (bid < 9024)  { src = w;  dst = wd;  bid -= 1024; }
  else if (bid < 10048) { src = rx; dst = rxd; bid -= 9024; }
  else                  { src = rw; dst = rwd; bid -= 10048; }

  int idx = bid * 256 + threadIdx.x;   // one 16-byte output block per thread
  int row = idx >> 6;                  // 64 blocks of 16 per 1024-byte row
  int b   = idx & 63;
  int chunk = b >> 3;                  // 128B chunk (8 per row)
  int c = b & 7;
  int p = c ^ (row & 7);

  const float* s = src + ((size_t)row << 10) + (b << 4);
  float4 v0 = *(const float4*)(s);
  float4 v1 = *(const float4*)(s + 4);
  float4 v2 = *(const float4*)(s + 8);
  float4 v3 = *(const float4*)(s + 12);
  int w0 = __builtin_amdgcn_cvt_pk_fp8_f32(v0.x, v0.y, 0, false);
  w0     = __builtin_amdgcn_cvt_pk_fp8_f32(v0.z, v0.w, w0, true);
  int w1 = __builtin_amdgcn_cvt_pk_fp8_f32(v1.x, v1.y, 0, false);
  w1     = __builtin_amdgcn_cvt_pk_fp8_f32(v1.z, v1.w, w1, true);
  int w2 = __builtin_amdgcn_cvt_pk_fp8_f32(v2.x, v2.y, 0, false);
  w2     = __builtin_amdgcn_cvt_pk_fp8_f32(v2.z, v2.w, w2, true);
  int w3 = __builtin_amdgcn_cvt_pk_fp8_f32(v3.x, v3.y, 0, false);
  w3     = __builtin_amdgcn_cvt_pk_fp8_f32(v3.z, v3.w, w3, true);
  int4 o = { w0, w1, w2, w3 };
  *(int4*)&dst[((size_t)row << 10) + (chunk << 7) + (p << 4)] = o;
}

// Fused fp8 GEMM (MX-scaled, unity scales) + per-row (max, sum-exp) partials
// over each 128-col vocab tile. blockIdx.z selects model.
__global__ __launch_bounds__(256) void lse_gemm_kernel(
    const char* __restrict__ X0, const char* __restrict__ W0,
    const char* __restrict__ X1, const char* __restrict__ W1,
    float2* __restrict__ P0, float2* __restrict__ P1)
{
  __shared__ char As[BM * BKB];   // 16 KB
  __shared__ char Bs[BN * BKB];   // 16 KB

  const char* Xp = blockIdx.z ? X1 : X0;
  const char* Wp = blockIdx.z ? W1 : W0;
  float2* Pp = blockIdx.z ? P1 : P0;

  const int tid    = threadIdx.x;
  const int m_base = blockIdx.x * BM;
  const int v_base = blockIdx.y * BN;

  const int wave = tid >> 6;
  const int lane = tid & 63;
  const int quad = lane >> 4;
  const int lc   = lane & 15;
  const int rb   = (wave & 1) * 64;   // token sub-block of this wave
  const int cb   = (wave >> 1) * 64;  // vocab sub-block of this wave

  // Staging: wave covers rows [wave*32, wave*32+32), 4 instrs x (64 lanes x 16B).
  const int srow = lane >> 3;         // row within 8-row group
  const int sp   = lane & 7;          // physical 16B block (global is pre-swizzled)
  const char* gA[4];
  const char* gB[4];
#pragma unroll
  for (int l = 0; l < 4; ++l) {
    int r8  = wave * 4 + l;
    int row = r8 * 8 + srow;
    gA[l] = Xp + (size_t)(m_base + row) * kH + sp * 16;
    gB[l] = Wp + (size_t)(v_base + row) * kH + sp * 16;
  }

  // Fragment LDS byte offsets. A-lane holds A[m=lane&15][k=quad*32+j], j=0..31:
  // two 16B halves at logical blocks quad*2, quad*2+1, XOR-unswizzled by row.
  int offA[4][2], offB[4][2];
#pragma unroll
  for (int i = 0; i < 4; ++i) {
    int ra = rb + i * 16 + lc;
    int rn = cb + i * 16 + lc;
#pragma unroll
    for (int s = 0; s < 2; ++s) {
      offA[i][s] = ra * BKB + ((((quad << 1) | s) ^ (ra & 7)) << 4);
      offB[i][s] = rn * BKB + ((((quad << 1) | s) ^ (rn & 7)) << 4);
    }
  }

  f32x4 acc[4][4];
#pragma unroll
  for (int i = 0; i < 4; ++i)
#pragma unroll
    for (int j = 0; j < 4; ++j) acc[i][j] = (f32x4){0.f, 0.f, 0.f, 0.f};

  for (int ks = 0; ks < kH / BKB; ++ks) {
#pragma unroll
    for (int l = 0; l < 4; ++l) {
      int r8 = wave * 4 + l;
      __builtin_amdgcn_global_load_lds((gvoid_t*)gA[l], (lvoid_t*)&As[r8 * 1024], 16, 0, 0);
      __builtin_amdgcn_global_load_lds((gvoid_t*)gB[l], (lvoid_t*)&Bs[r8 * 1024], 16, 0, 0);
      gA[l] += BKB;
      gB[l] += BKB;
    }
    __syncthreads();

    v8i a[4], b[4];
#pragma unroll
    for (int i = 0; i < 4; ++i) {
      int4 lo = *(const int4*)&As[offA[i][0]];
      int4 hi = *(const int4*)&As[offA[i][1]];
      a[i] = (v8i){lo.x, lo.y, lo.z, lo.w, hi.x, hi.y, hi.z, hi.w};
    }
#pragma unroll
    for (int j = 0; j < 4; ++j) {
      int4 lo = *(const int4*)&Bs[offB[j][0]];
      int4 hi = *(const int4*)&Bs[offB[j][1]];
      b[j] = (v8i){lo.x, lo.y, lo.z, lo.w, hi.x, hi.y, hi.z, hi.w};
    }
#pragma unroll
    for (int i = 0; i < 4; ++i)
#pragma unroll
      for (int j = 0; j < 4; ++j)
        acc[i][j] = __builtin_amdgcn_mfma_scale_f32_16x16x128_f8f6f4(
            a[i], b[j], acc[i][j], 0, 0, /*opsel_a*/0, /*scale_a*/127,
            /*opsel_b*/0, /*scale_b*/127);
    __syncthreads();
  }

  // Epilogue: per-token max & sum-exp over this block's 128 vocab cols.
  // C/D layout (16x16 family, dtype-independent): row = quad*4+reg, col = lane&15.
  float* redm = (float*)As;        // reuse LDS: 2 planes x 128 floats each
  float* reds = redm + 256;
#pragma unroll
  for (int i = 0; i < 4; ++i) {
#pragma unroll
    for (int r = 0; r < 4; ++r) {
      int row_local = rb + i * 16 + quad * 4 + r;
      float v0 = acc[i][0][r], v1 = acc[i][1][r], v2 = acc[i][2][r], v3 = acc[i][3][r];
      float m = fmaxf(fmaxf(v0, v1), fmaxf(v2, v3));
#pragma unroll
      for (int st = 1; st < 16; st <<= 1) m = fmaxf(m, __shfl_xor(m, st, 16));
      float s = __expf(v0 - m) + __expf(v1 - m) + __expf(v2 - m) + __expf(v3 - m);
#pragma unroll
      for (int st = 1; st < 16; st <<= 1) s += __shfl_xor(s, st, 16);
      if (lc == 0) { redm[(wave >> 1) * 128 + row_local] = m; reds[(wave >> 1) * 128 + row_local] = s; }
    }
  }
  __syncthreads();
  if (tid < BM) {
    float m1 = redm[tid], s1 = reds[tid];
    float m2 = redm[128 + tid], s2 = reds[128 + tid];
    float M = fmaxf(m1, m2);
    float S = s1 * __expf(m1 - M) + s2 * __expf(m2 - M);
    Pp[(size_t)blockIdx.y * kTok + m_base + tid] = make_float2(M, S);
  }
}

// Exact fp32 selected-logit from the ORIGINAL fp32 inputs.
__global__ __launch_bounds__(256) void sel_kernel(
    const float* __restrict__ X0, const float* __restrict__ W0,
    const float* __restrict__ X1, const float* __restrict__ W1,
    const int* __restrict__ ids, float* __restrict__ sel0, float* __restrict__ sel1)
{
  const int model = blockIdx.y;
  const float* X = model ? X1 : X0;
  const float* W = model ? W1 : W0;
  float* out = model ? sel1 : sel0;
  const int wave = threadIdx.x >> 6, lane = threadIdx.x & 63;
  const int t  = blockIdx.x * 4 + wave;
  const int id = ids[t];
  const float* xr = X + (size_t)t * kH;
  const float* wr = W + (size_t)id * kH;
  float s = 0.f;
#pragma unroll
  for (int r = 0; r < 4; ++r) {
    int idx = r * 256 + lane * 4;
    float4 a = *(const float4*)&xr[idx];
    float4 b = *(const float4*)&wr[idx];
    s += a.x * b.x + a.y * b.y + a.z * b.z + a.w * b.w;
  }
#pragma unroll
  for (int st = 32; st; st >>= 1) s += __shfl_xor(s, st, 64);
  if (lane == 0) out[t] = s;
}

// Combine 250 partials/model -> lse; GRPO loss; reduce.
__global__ __launch_bounds__(256) void finalize_kernel(
    const float2* __restrict__ P0, const float2* __restrict__ P1,
    const float* __restrict__ sel0, const float* __restrict__ sel1,
    const float* __restrict__ adv, const int* __restrict__ mask,
    float* __restrict__ accum)
{
  const int t = blockIdx.x * 256 + threadIdx.x;
  float M0 = -INFINITY, S0 = 0.f, M1 = -INFINITY, S1 = 0.f;
  for (int i = 0; i < NVT; ++i) {
    float2 p = P0[(size_t)i * kTok + t];
    if (p.x > M0) { S0 = S0 * __expf(M0 - p.x) + p.y; M0 = p.x; }
    else          { S0 += p.y * __expf(p.x - M0); }
  }
  for (int i = 0; i < NVT; ++i) {
    float2 p = P1[(size_t)i * kTok + t];
    if (p.x > M1) { S1 = S1 * __expf(M1 - p.x) + p.y; M1 = p.x; }
    else          { S1 += p.y * __expf(p.x - M1); }
  }
  float lse0  = M0 + logf(S0);
  float lse1  = M1 + logf(S1);
  float logp  = sel0[t] - lse0;
  float rlogp = sel1[t] - lse1;
  float d  = rlogp - logp;
  float kl = __expf(d) - d - 1.f;
  // coef_1 = exp(logp - stopgrad(logp)) == 1, clip == 1 -> loss = -adv + beta*kl
  float a  = adv[t >> 10];
  float mv = (float)mask[t];
  float loss = (-a + 0.1f * kl) * mv;

#pragma unroll
  for (int st = 32; st; st >>= 1) {
    loss += __shfl_xor(loss, st, 64);
    mv   += __shfl_xor(mv, st, 64);
  }
  __shared__ float lsum[4], msum[4];
  const int wave = threadIdx.x >> 6, lane = threadIdx.x & 63;
  if (lane == 0) { lsum[wave] = loss; msum[wave] = mv; }
  __syncthreads();
  if (threadIdx.x == 0) {
    atomicAdd(&accum[0], lsum[0] + lsum[1] + lsum[2] + lsum[3]);
    atomicAdd(&accum[1], msum[0] + msum[1] + msum[2] + msum[3]);
  }
}

__global__ void scalar_kernel(const float* __restrict__ accum, float* __restrict__ out)
{
  out[0] = accum[0] / fmaxf(accum[1], 1.f);
}

extern "C" void kernel_launch(void* const* d_in, const int* in_sizes, int n_in,
                              void* d_out, int out_size, void* d_ws, size_t ws_size,
                              hipStream_t stream)
{
  const float* x    = (const float*)d_in[0];
  const float* w    = (const float*)d_in[1];
  const float* rx   = (const float*)d_in[2];
  const float* rw   = (const float*)d_in[3];
  const float* adv  = (const float*)d_in[4];
  const int*   ids  = (const int*)d_in[5];
  const int*   mask = (const int*)d_in[6];
  float* out = (float*)d_out;

  // Workspace (~90 MB): fp8 copies + partials + sel + accum.
  char* ws = (char*)d_ws;
  char* Xq  = ws;                                   // 4 MB
  char* Wq  = Xq + (size_t)kTok * kH;               // 32 MB
  char* RXq = Wq + (size_t)kV * kH;                 // 4 MB
  char* RWq = RXq + (size_t)kTok * kH;              // 32 MB
  float2* P0 = (float2*)(RWq + (size_t)kV * kH);    // 8 MB
  float2* P1 = P0 + (size_t)NVT * kTok;             // 8 MB
  float*  sel0 = (float*)(P1 + (size_t)NVT * kTok);
  float*  sel1 = sel0 + kTok;
  float*  accum = sel1 + kTok;

  hipMemsetAsync(accum, 0, 2 * sizeof(float), stream);

  convert_kernel<<<18048, 256, 0, stream>>>(x, Xq, w, Wq, rx, RXq, rw, RWq);

  sel_kernel<<<dim3(kTok / 4, 2), 256, 0, stream>>>(x, w, rx, rw, ids, sel0, sel1);

  lse_gemm_kernel<<<dim3(NMT, NVT, 2), 256, 0, stream>>>(Xq, Wq, RXq, RWq, P0, P1);

  finalize_kernel<<<kTok / 256, 256, 0, stream>>>(P0, P1, sel0, sel1, adv, mask, accum);
  scalar_kernel<<<1, 1, 0, stream>>>(accum, out);
}